// Round 1
// baseline (2246.414 us; speedup 1.0000x reference)
//
#include <hip/hip_runtime.h>

#define DFEAT 64

// ---------------- degree / normalization ----------------

__global__ void k_init_deg(float* __restrict__ deg, int n) {
    int i = blockIdx.x * blockDim.x + threadIdx.x;
    if (i < n) deg[i] = 1.0f;   // self-loop contributes 1
}

__global__ void k_count_deg(float* __restrict__ deg, const int* __restrict__ dst, int E) {
    int e = blockIdx.x * blockDim.x + threadIdx.x;
    if (e < E) atomicAdd(&deg[dst[e]], 1.0f);
}

__global__ void k_make_dis(float* __restrict__ deg, int n) {
    int i = blockIdx.x * blockDim.x + threadIdx.x;
    if (i < n) deg[i] = rsqrtf(deg[i]);   // deg >= 1 always (self-loop)
}

// ---------------- tall-skinny GEMM: g = (X @ W) * dis, agg = g ----------------
// One block computes a 64x64 output tile. W (64x64) and the X tile staged in LDS.

__global__ __launch_bounds__(256) void k_gemm_scale(
    const float* __restrict__ X, const float* __restrict__ W,
    const float* __restrict__ dis, float* __restrict__ g,
    float* __restrict__ agg, int n) {
    __shared__ float Ws[64 * 64];
    __shared__ float Xs[64 * 64];

    for (int i = threadIdx.x; i < 64 * 64; i += 256) Ws[i] = W[i];

    int row0 = blockIdx.x * 64;
    int rows = n - row0; if (rows > 64) rows = 64;
    for (int i = threadIdx.x; i < rows * 64; i += 256)
        Xs[i] = X[(size_t)row0 * 64 + i];
    __syncthreads();

    int d  = threadIdx.x & 63;   // output column (lane)
    int rg = threadIdx.x >> 6;   // row group 0..3, 16 rows each

    float acc[16];
#pragma unroll
    for (int r = 0; r < 16; ++r) acc[r] = 0.f;

#pragma unroll 16
    for (int k = 0; k < 64; ++k) {
        float w = Ws[k * 64 + d];          // 64 consecutive floats: conflict-free
#pragma unroll
        for (int r = 0; r < 16; ++r)
            acc[r] = fmaf(Xs[(rg * 16 + r) * 64 + k], w, acc[r]);  // broadcast read
    }

#pragma unroll
    for (int r = 0; r < 16; ++r) {
        int row = rg * 16 + r;
        if (row < rows) {
            float val = acc[r] * dis[row0 + row];
            size_t o = (size_t)(row0 + row) * 64 + d;
            g[o]   = val;   // stable copy read by the edge kernel
            agg[o] = val;   // accumulator init = self-loop term
        }
    }
}

// ---------------- edge scatter: agg[dst] += g[src] ----------------
// 16 lanes per edge, float4 gather, 4 scalar f32 atomics per lane.

__global__ __launch_bounds__(256) void k_edge_scatter(
    const float* __restrict__ g, float* __restrict__ agg,
    const int* __restrict__ src, const int* __restrict__ dst, int E) {
    int t = blockIdx.x * blockDim.x + threadIdx.x;
    int e = t >> 4;
    if (e >= E) return;
    int q = (t & 15) * 4;
    int s = src[e];
    int d = dst[e];
    float4 v = *reinterpret_cast<const float4*>(g + (size_t)s * DFEAT + q);
    float* out = agg + (size_t)d * DFEAT + q;
    atomicAdd(out + 0, v.x);
    atomicAdd(out + 1, v.y);
    atomicAdd(out + 2, v.z);
    atomicAdd(out + 3, v.w);
}

// ---------------- epilogues ----------------
// out = relu(agg * dis + b)          (k_act)
// out = relu(agg * dis + b) + x      (k_final)

__global__ __launch_bounds__(256) void k_act(
    const float* __restrict__ agg, const float* __restrict__ dis,
    const float* __restrict__ bias, float* __restrict__ out, int n) {
    int i = blockIdx.x * blockDim.x + threadIdx.x;   // over n*16 float4s
    if (i >= n * 16) return;
    int v  = i >> 4;
    int dq = (i & 15) * 4;
    float s = dis[v];
    float4 a = *reinterpret_cast<const float4*>(agg + (size_t)i * 4);
    float4 r;
    r.x = fmaxf(fmaf(a.x, s, bias[dq + 0]), 0.f);
    r.y = fmaxf(fmaf(a.y, s, bias[dq + 1]), 0.f);
    r.z = fmaxf(fmaf(a.z, s, bias[dq + 2]), 0.f);
    r.w = fmaxf(fmaf(a.w, s, bias[dq + 3]), 0.f);
    *reinterpret_cast<float4*>(out + (size_t)i * 4) = r;
}

__global__ __launch_bounds__(256) void k_final(
    const float* __restrict__ agg, const float* __restrict__ dis,
    const float* __restrict__ bias, const float* __restrict__ x,
    float* __restrict__ out, int n) {
    int i = blockIdx.x * blockDim.x + threadIdx.x;
    if (i >= n * 16) return;
    int v  = i >> 4;
    int dq = (i & 15) * 4;
    float s = dis[v];
    float4 a  = *reinterpret_cast<const float4*>(agg + (size_t)i * 4);
    float4 xi = *reinterpret_cast<const float4*>(x   + (size_t)i * 4);
    float4 r;
    r.x = fmaxf(fmaf(a.x, s, bias[dq + 0]), 0.f) + xi.x;
    r.y = fmaxf(fmaf(a.y, s, bias[dq + 1]), 0.f) + xi.y;
    r.z = fmaxf(fmaf(a.z, s, bias[dq + 2]), 0.f) + xi.z;
    r.w = fmaxf(fmaf(a.w, s, bias[dq + 3]), 0.f) + xi.w;
    *reinterpret_cast<float4*>(out + (size_t)i * 4) = r;
}

// ---------------- launch ----------------

extern "C" void kernel_launch(void* const* d_in, const int* in_sizes, int n_in,
                              void* d_out, int out_size, void* d_ws, size_t ws_size,
                              hipStream_t stream) {
    const float* x  = (const float*)d_in[0];
    const int*   ei = (const int*)  d_in[1];
    const float* W1 = (const float*)d_in[2];
    const float* b1 = (const float*)d_in[3];
    const float* W2 = (const float*)d_in[4];
    const float* b2 = (const float*)d_in[5];
    float* out = (float*)d_out;

    const int n = in_sizes[0] / DFEAT;     // 100000
    const int E = in_sizes[1] / 2;         // 1250000
    const int* src = ei;
    const int* dst = ei + E;

    const size_t nd = (size_t)n * DFEAT;
    float* ws  = (float*)d_ws;
    float* dis = ws;            // n floats (doubles as deg scratch)
    float* A   = ws + n;        // g  buffer, n*64
    float* B   = A + nd;        // agg buffer, n*64
    float* C   = B + nd;        // layer-1 activation, n*64

    const int B256 = 256;
    const int gN   = (n + B256 - 1) / B256;
    const int gE   = (E + B256 - 1) / B256;
    const int gT   = (n + 63) / 64;                    // gemm tiles
    const int gEd  = (int)(((size_t)E * 16 + B256 - 1) / B256);
    const int gAct = (n * 16 + B256 - 1) / B256;

    // normalization
    k_init_deg <<<gN, B256, 0, stream>>>(dis, n);
    k_count_deg<<<gE, B256, 0, stream>>>(dis, dst, E);
    k_make_dis <<<gN, B256, 0, stream>>>(dis, n);

    // layer 1
    k_gemm_scale  <<<gT,  B256, 0, stream>>>(x, W1, dis, A, B, n);
    k_edge_scatter<<<gEd, B256, 0, stream>>>(A, B, src, dst, E);
    k_act         <<<gAct, B256, 0, stream>>>(B, dis, b1, C, n);

    // layer 2
    k_gemm_scale  <<<gT,  B256, 0, stream>>>(C, W2, dis, A, B, n);
    k_edge_scatter<<<gEd, B256, 0, stream>>>(A, B, src, dst, E);
    k_final       <<<gAct, B256, 0, stream>>>(B, dis, b2, x, out, n);
}

// Round 3
// 449.375 us; speedup vs baseline: 4.9990x; 4.9990x over previous
//
#include <hip/hip_runtime.h>

#define DFEAT 64
#define SCAN_CHUNK 2048

// ======================= CSR build =======================

__global__ void k_zero(int* __restrict__ c, int n) {
    int i = blockIdx.x * blockDim.x + threadIdx.x;
    if (i < n) c[i] = 0;
}

__global__ void k_hist(int* __restrict__ cnt, const int* __restrict__ dst, int E) {
    int e = blockIdx.x * blockDim.x + threadIdx.x;
    if (e < E) atomicAdd(&cnt[dst[e]], 1);
}

// per-chunk (2048 elems) sums
__global__ __launch_bounds__(256) void k_scan1(
    const int* __restrict__ cnt, int* __restrict__ partial, int n) {
    __shared__ int lds[256];
    int base = blockIdx.x * SCAN_CHUNK + threadIdx.x * 8;
    int t = 0;
#pragma unroll
    for (int j = 0; j < 8; ++j) { int idx = base + j; if (idx < n) t += cnt[idx]; }
    lds[threadIdx.x] = t; __syncthreads();
    for (int s = 128; s > 0; s >>= 1) {
        if (threadIdx.x < s) lds[threadIdx.x] += lds[threadIdx.x + s];
        __syncthreads();
    }
    if (threadIdx.x == 0) partial[blockIdx.x] = lds[0];
}

// exclusive scan of the (tiny) partials array; also writes row_ptr[n] = E
__global__ void k_scan2(int* __restrict__ partial, int nb, int* __restrict__ row_ptr, int n) {
    if (threadIdx.x == 0 && blockIdx.x == 0) {
        int run = 0;
        for (int b = 0; b < nb; ++b) { int v = partial[b]; partial[b] = run; run += v; }
        row_ptr[n] = run;
    }
}

// full exclusive scan -> row_ptr and cursor
__global__ __launch_bounds__(256) void k_scan3(
    const int* __restrict__ cnt, const int* __restrict__ partial,
    int* __restrict__ row_ptr, int* __restrict__ cursor, int n) {
    __shared__ int lds[256];
    int base = blockIdx.x * SCAN_CHUNK + threadIdx.x * 8;
    int local[8]; int t = 0;
#pragma unroll
    for (int j = 0; j < 8; ++j) {
        int idx = base + j; int v = (idx < n) ? cnt[idx] : 0; local[j] = v; t += v;
    }
    lds[threadIdx.x] = t; __syncthreads();
    if (threadIdx.x == 0) {                       // 256-elem sequential scan in LDS (cheap, 49 blocks in parallel)
        int run = partial[blockIdx.x];
        for (int i = 0; i < 256; ++i) { int v = lds[i]; lds[i] = run; run += v; }
    }
    __syncthreads();
    int run = lds[threadIdx.x];
#pragma unroll
    for (int j = 0; j < 8; ++j) {
        int idx = base + j;
        if (idx < n) { row_ptr[idx] = run; cursor[idx] = run; run += local[j]; }
    }
}

__global__ void k_make_dis(const int* __restrict__ cnt, float* __restrict__ dis, int n) {
    int i = blockIdx.x * blockDim.x + threadIdx.x;
    if (i < n) dis[i] = rsqrtf((float)cnt[i] + 1.0f);   // +1 self-loop
}

__global__ void k_fill(int* __restrict__ cursor, const int* __restrict__ src,
                       const int* __restrict__ dst, int* __restrict__ col, int E) {
    int e = blockIdx.x * blockDim.x + threadIdx.x;
    if (e >= E) return;
    int p = atomicAdd(&cursor[dst[e]], 1);
    col[p] = src[e];
}

// ============ tall-skinny GEMM: g = (X @ W) * dis ============

__global__ __launch_bounds__(256) void k_gemm_scale(
    const float* __restrict__ X, const float* __restrict__ W,
    const float* __restrict__ dis, float* __restrict__ g, int n) {
    __shared__ float Ws[64 * 64];
    __shared__ float Xs[64 * 64];

    for (int i = threadIdx.x; i < 64 * 64; i += 256) Ws[i] = W[i];

    int row0 = blockIdx.x * 64;
    int rows = n - row0; if (rows > 64) rows = 64;
    for (int i = threadIdx.x; i < rows * 64; i += 256)
        Xs[i] = X[(size_t)row0 * 64 + i];
    __syncthreads();

    int d  = threadIdx.x & 63;
    int rg = threadIdx.x >> 6;

    float acc[16];
#pragma unroll
    for (int r = 0; r < 16; ++r) acc[r] = 0.f;

#pragma unroll 16
    for (int k = 0; k < 64; ++k) {
        float w = Ws[k * 64 + d];
#pragma unroll
        for (int r = 0; r < 16; ++r)
            acc[r] = fmaf(Xs[(rg * 16 + r) * 64 + k], w, acc[r]);
    }

#pragma unroll
    for (int r = 0; r < 16; ++r) {
        int row = rg * 16 + r;
        if (row < rows)
            g[(size_t)(row0 + row) * 64 + d] = acc[r] * dis[row0 + row];
    }
}

// ======= fused aggregate + epilogue: out = relu(dis[v]*(g[v]+Σg[nbr]) + b) [+ resid] =======
// One wave per node; lane = feature. Coalesced 256B row gathers, no atomics.

__global__ __launch_bounds__(256) void k_aggregate(
    const float* __restrict__ g, const int* __restrict__ row_ptr,
    const int* __restrict__ col, const float* __restrict__ dis,
    const float* __restrict__ bias, const float* __restrict__ resid,
    float* __restrict__ out, int n) {
    int node = blockIdx.x * 4 + (threadIdx.x >> 6);
    if (node >= n) return;
    int lane = threadIdx.x & 63;

    int beg = row_ptr[node], end = row_ptr[node + 1];
    float acc = g[(size_t)node * DFEAT + lane];     // self-loop term

    int i = beg;
    for (; i + 4 <= end; i += 4) {                  // 4 independent gathers in flight
        int s0 = col[i], s1 = col[i + 1], s2 = col[i + 2], s3 = col[i + 3];
        float v0 = g[(size_t)s0 * DFEAT + lane];
        float v1 = g[(size_t)s1 * DFEAT + lane];
        float v2 = g[(size_t)s2 * DFEAT + lane];
        float v3 = g[(size_t)s3 * DFEAT + lane];
        acc += v0; acc += v1; acc += v2; acc += v3;
    }
    for (; i < end; ++i) acc += g[(size_t)col[i] * DFEAT + lane];

    float v = fmaxf(fmaf(acc, dis[node], bias[lane]), 0.f);
    if (resid) v += resid[(size_t)node * DFEAT + lane];
    out[(size_t)node * DFEAT + lane] = v;
}

// ======================= launch =======================

extern "C" void kernel_launch(void* const* d_in, const int* in_sizes, int n_in,
                              void* d_out, int out_size, void* d_ws, size_t ws_size,
                              hipStream_t stream) {
    const float* x  = (const float*)d_in[0];
    const int*   ei = (const int*)  d_in[1];
    const float* W1 = (const float*)d_in[2];
    const float* b1 = (const float*)d_in[3];
    const float* W2 = (const float*)d_in[4];
    const float* b2 = (const float*)d_in[5];
    float* out = (float*)d_out;

    const int n = in_sizes[0] / DFEAT;     // 100000
    const int E = in_sizes[1] / 2;         // 1250000
    const int* src = ei;
    const int* dst = ei + E;

    const int NB = (n + SCAN_CHUNK - 1) / SCAN_CHUNK;

    // workspace carve-up (all 4-byte elems; pad boundaries to 4-elem multiples)
    int*   cnt     = (int*)d_ws;                         // n
    int*   partial = cnt + ((n + 3) & ~3);               // NB
    int*   row_ptr = partial + ((NB + 3) & ~3);          // n+1
    int*   cursor  = row_ptr + ((n + 1 + 3) & ~3);       // n
    int*   col     = cursor + ((n + 3) & ~3);            // E
    float* dis     = (float*)(col + ((E + 3) & ~3));     // n
    float* g       = dis + ((n + 3) & ~3);               // n*64
    float* h       = g + (size_t)n * DFEAT;              // n*64

    const int B256 = 256;
    const int gN  = (n + B256 - 1) / B256;
    const int gE  = (E + B256 - 1) / B256;
    const int gT  = (n + 63) / 64;
    const int gAg = (n + 3) / 4;

    // ---- CSR build + normalization (once) ----
    k_zero    <<<gN, B256, 0, stream>>>(cnt, n);
    k_hist    <<<gE, B256, 0, stream>>>(cnt, dst, E);
    k_scan1   <<<NB, B256, 0, stream>>>(cnt, partial, n);
    k_scan2   <<<1,  64,   0, stream>>>(partial, NB, row_ptr, n);
    k_scan3   <<<NB, B256, 0, stream>>>(cnt, partial, row_ptr, cursor, n);
    k_make_dis<<<gN, B256, 0, stream>>>(cnt, dis, n);
    k_fill    <<<gE, B256, 0, stream>>>(cursor, src, dst, col, E);

    // ---- layer 1 ----
    k_gemm_scale<<<gT,  B256, 0, stream>>>(x, W1, dis, g, n);
    k_aggregate <<<gAg, B256, 0, stream>>>(g, row_ptr, col, dis, b1, nullptr, h, n);

    // ---- layer 2 ----
    k_gemm_scale<<<gT,  B256, 0, stream>>>(h, W2, dis, g, n);
    k_aggregate <<<gAg, B256, 0, stream>>>(g, row_ptr, col, dis, b2, x, out, n);
}